// Round 1
// baseline (74.900 us; speedup 1.0000x reference)
//
#include <hip/hip_runtime.h>

#define NUM_INPUTS 4096
#define NUM_LEAVES 2048

// out[b, l] = x[b, idx[l]]
// One block per batch row: stage the 16 KiB row in LDS (coalesced float4
// reads), gather from LDS, write coalesced float4 stores.
__global__ __launch_bounds__(256) void FrozenInputToLeaf_gather(
    const float* __restrict__ x,
    const int* __restrict__ idx,
    float* __restrict__ out) {
    __shared__ float row[NUM_INPUTS];

    const int b = blockIdx.x;
    const int t = threadIdx.x;

    // Stage row b of x into LDS: 4096 floats = 1024 float4, 256 threads -> 4 each.
    const float4* __restrict__ xv = (const float4*)(x + (size_t)b * NUM_INPUTS);
    float4* rv = (float4*)row;
#pragma unroll
    for (int j = 0; j < 4; ++j) {
        rv[t + j * 256] = xv[t + j * 256];
    }
    __syncthreads();

    // Each thread produces 8 contiguous outputs: leaves 8t .. 8t+7.
    // idx loads are vectorized int4 (L2-hot, only 8 KiB total).
    const int4* __restrict__ iv = (const int4*)idx;
    const int4 i0 = iv[t * 2 + 0];
    const int4 i1 = iv[t * 2 + 1];

    float4 o0, o1;
    o0.x = row[i0.x];
    o0.y = row[i0.y];
    o0.z = row[i0.z];
    o0.w = row[i0.w];
    o1.x = row[i1.x];
    o1.y = row[i1.y];
    o1.z = row[i1.z];
    o1.w = row[i1.w];

    float4* __restrict__ ov = (float4*)(out + (size_t)b * NUM_LEAVES);
    ov[t * 2 + 0] = o0;
    ov[t * 2 + 1] = o1;
}

extern "C" void kernel_launch(void* const* d_in, const int* in_sizes, int n_in,
                              void* d_out, int out_size, void* d_ws, size_t ws_size,
                              hipStream_t stream) {
    const float* x = (const float*)d_in[0];
    const int* idx = (const int*)d_in[1];
    float* out = (float*)d_out;

    const int batch = in_sizes[0] / NUM_INPUTS;  // 16384

    FrozenInputToLeaf_gather<<<batch, 256, 0, stream>>>(x, idx, out);
}

// Round 2
// 74.481 us; speedup vs baseline: 1.0056x; 1.0056x over previous
//
#include <hip/hip_runtime.h>

#define NUM_INPUTS 4096
#define NUM_LEAVES 2048
#define ROWS_PER_BLOCK 2
#define BLK 256

typedef const __attribute__((address_space(1))) void* gas_ptr;
typedef __attribute__((address_space(3))) void* las_ptr;

// out[b, l] = x[b, idx[l]]
// 2 rows per block: idx loaded once, rows staged global->LDS via
// global_load_lds (width 16, no VGPR round trip), one barrier per 2 rows,
// gather from LDS, coalesced float4 stores.
__global__ __launch_bounds__(BLK) void FrozenInputToLeaf_gather2(
    const float* __restrict__ x,
    const int* __restrict__ idx,
    float* __restrict__ out) {
    __shared__ float rows[ROWS_PER_BLOCK][NUM_INPUTS];

    const int t = threadIdx.x;
    const size_t b0 = (size_t)blockIdx.x * ROWS_PER_BLOCK;

    // Load indices once per block (8 KiB, L2/L3-hot across all blocks).
    const int4* __restrict__ iv = (const int4*)idx;
    const int4 i0 = iv[t * 2 + 0];
    const int4 i1 = iv[t * 2 + 1];

    // Stage ROWS_PER_BLOCK rows (16 KiB each) directly global->LDS.
    // Per row: 1024 x 16B segments; 256 threads x 4 iters. Lane pattern is
    // wave-uniform base + lane*16B — exactly what global_load_lds requires.
#pragma unroll
    for (int r = 0; r < ROWS_PER_BLOCK; ++r) {
        const float* __restrict__ src = x + (b0 + r) * NUM_INPUTS;
#pragma unroll
        for (int j = 0; j < 4; ++j) {
            const int e = (j * BLK + threadIdx.x) * 4;  // float index of this lane's 16B
            __builtin_amdgcn_global_load_lds((gas_ptr)(src + e),
                                             (las_ptr)(&rows[r][e]), 16, 0, 0);
        }
    }
    __syncthreads();  // compiler emits the vmcnt(0) drain before s_barrier

#pragma unroll
    for (int r = 0; r < ROWS_PER_BLOCK; ++r) {
        float4 o0, o1;
        o0.x = rows[r][i0.x];
        o0.y = rows[r][i0.y];
        o0.z = rows[r][i0.z];
        o0.w = rows[r][i0.w];
        o1.x = rows[r][i1.x];
        o1.y = rows[r][i1.y];
        o1.z = rows[r][i1.z];
        o1.w = rows[r][i1.w];

        float4* __restrict__ ov = (float4*)(out + (b0 + r) * NUM_LEAVES);
        ov[t * 2 + 0] = o0;
        ov[t * 2 + 1] = o1;
    }
}

extern "C" void kernel_launch(void* const* d_in, const int* in_sizes, int n_in,
                              void* d_out, int out_size, void* d_ws, size_t ws_size,
                              hipStream_t stream) {
    const float* x = (const float*)d_in[0];
    const int* idx = (const int*)d_in[1];
    float* out = (float*)d_out;

    const int batch = in_sizes[0] / NUM_INPUTS;  // 16384
    const int grid = batch / ROWS_PER_BLOCK;     // 8192

    FrozenInputToLeaf_gather2<<<grid, BLK, 0, stream>>>(x, idx, out);
}